// Round 16
// baseline (428.993 us; speedup 1.0000x reference)
//
#include <hip/hip_runtime.h>
#include <hip/hip_bf16.h>

// Problem constants (from reference source)
#define REGION_R0 42033
#define REGION_R1 44630
#define RN        (REGION_R1 - REGION_R0)   // 2597
#define CH        64
#define KSPLIT    32
#define ROW_TILES ((RN + 31) / 32)          // 82
#define SCAN_B    256
#define NSLICE    8                          // XCD count / round-robin period
#define SLICE_RB  128                        // range-blocks per slice (1024 total, co-resident)

// MFMA region-gemm geometry
#define KTT       82                         // ceil(RN/32) K-steps
#define KP        (KTT * 32)                 // 2624 padded K
#define PERCHUNK  6
#define KCHUNKS   14                         // ceil(82/6)
#define MT_TILES  163                        // ceil(RN/16)
#define MT_BLKS   41                         // ceil(163/4)

typedef unsigned short ushort_t;
typedef short  bfrag8 __attribute__((ext_vector_type(8)));   // 8 bf16 (4 VGPR)
typedef float  f32x4v __attribute__((ext_vector_type(4)));

// =========================================================================
// Region blend init (region_ent = 0.8 * orig)
// =========================================================================
__global__ void region_init_kernel(const float* __restrict__ emb,
                                   float* __restrict__ region_ent) {
    const int gid = blockIdx.x * blockDim.x + threadIdx.x;
    if (gid >= RN * CH / 4) return;
    const float4 v = reinterpret_cast<const float4*>(emb + (size_t)REGION_R0 * CH)[gid];
    float4 o;
    o.x = 0.8f * v.x; o.y = 0.8f * v.y; o.z = 0.8f * v.z; o.w = 0.8f * v.w;
    reinterpret_cast<float4*>(region_ent)[gid] = o;
}

__device__ __forceinline__ unsigned pack2bf(float a, float b) {
    unsigned ua = __float_as_uint(a);
    unsigned ub = __float_as_uint(b);
    ua += 0x7fffu + ((ua >> 16) & 1u);   // RNE
    ub += 0x7fffu + ((ub >> 16) & 1u);
    return ((ua >> 16) & 0xffffu) | (ub & 0xffff0000u);
}

// =========================================================================
// e_t[c][k] = bf16(emb[R0+k][c]), k padded to KP (B operand, transposed)
// =========================================================================
__global__ void build_et_kernel(const float* __restrict__ emb,
                                ushort_t* __restrict__ e_t) {
    const int gid = blockIdx.x * blockDim.x + threadIdx.x;
    if (gid >= CH * (KP / 8)) return;
    const int c  = gid / (KP / 8);
    const int k8 = gid - c * (KP / 8);
    const int kb = k8 * 8;
    float v[8];
#pragma unroll
    for (int j = 0; j < 8; ++j) {
        const int k = kb + j;
        v[j] = (k < RN) ? emb[(size_t)(REGION_R0 + k) * CH + c] : 0.0f;
    }
    uint4 o;
    o.x = pack2bf(v[0], v[1]); o.y = pack2bf(v[2], v[3]);
    o.z = pack2bf(v[4], v[5]); o.w = pack2bf(v[6], v[7]);
    *reinterpret_cast<uint4*>(e_t + (size_t)c * KP + kb) = o;
}

// =========================================================================
// MFMA region GEMM (R14: 92us VALU -> ~15us MFMA, verified absmax 0.25)
// =========================================================================
__global__ void region_gemm_mfma_kernel(const float* __restrict__ W,
                                        const ushort_t* __restrict__ e_t,
                                        float* __restrict__ region_ent) {
    const int wv    = threadIdx.x >> 6;
    const int lane  = threadIdx.x & 63;
    const int blk_m = blockIdx.x / KCHUNKS;
    const int kc    = blockIdx.x - blk_m * KCHUNKS;
    const int mt    = blk_m * 4 + wv;
    if (mt >= MT_TILES) return;
    const int l15 = lane & 15;
    const int lg  = lane >> 4;

    int arow = mt * 16 + l15;
    if (arow >= RN) arow = RN - 1;
    const float* wrow = W + (size_t)arow * RN;

    const int kt0 = kc * PERCHUNK;
    const int kt1 = (kt0 + PERCHUNK < KTT) ? (kt0 + PERCHUNK) : KTT;

    f32x4v acc[4];
#pragma unroll
    for (int n = 0; n < 4; ++n) acc[n] = (f32x4v){0.f, 0.f, 0.f, 0.f};

    for (int kt = kt0; kt < kt1; ++kt) {
        const int kb = kt * 32 + lg * 8;
        union { uint4 u; bfrag8 f; } A;
        if (kb + 8 <= RN) {
            float v0 = wrow[kb + 0], v1 = wrow[kb + 1];
            float v2 = wrow[kb + 2], v3 = wrow[kb + 3];
            float v4 = wrow[kb + 4], v5 = wrow[kb + 5];
            float v6 = wrow[kb + 6], v7 = wrow[kb + 7];
            A.u.x = pack2bf(v0, v1); A.u.y = pack2bf(v2, v3);
            A.u.z = pack2bf(v4, v5); A.u.w = pack2bf(v6, v7);
        } else {
            float v[8];
#pragma unroll
            for (int j = 0; j < 8; ++j) {
                const int k = kb + j;
                v[j] = (k < RN) ? wrow[k] : 0.0f;
            }
            A.u.x = pack2bf(v[0], v[1]); A.u.y = pack2bf(v[2], v[3]);
            A.u.z = pack2bf(v[4], v[5]); A.u.w = pack2bf(v[6], v[7]);
        }
#pragma unroll
        for (int n = 0; n < 4; ++n) {
            const bfrag8 B = *reinterpret_cast<const bfrag8*>(
                e_t + (size_t)(n * 16 + l15) * KP + kb);
            acc[n] = __builtin_amdgcn_mfma_f32_16x16x32_bf16(A.f, B, acc[n], 0, 0, 0);
        }
    }

#pragma unroll
    for (int n = 0; n < 4; ++n) {
#pragma unroll
        for (int j = 0; j < 4; ++j) {
            const int row = mt * 16 + lg * 4 + j;
            if (row < RN)
                unsafeAtomicAdd(region_ent + (size_t)row * CH + n * 16 + l15,
                                0.2f * acc[n][j]);
        }
    }
}

// =========================================================================
// Old VALU region GEMM (small-ws fallback only)
// =========================================================================
__global__ void region_gemm_kernel(const float* __restrict__ emb,
                                   const float* __restrict__ W,
                                   float* __restrict__ region_ent) {
    const int wave = threadIdx.x >> 6;
    const int c    = threadIdx.x & 63;
    const int rt   = blockIdx.x / KSPLIT;
    const int ks   = blockIdx.x - rt * KSPLIT;
    const int base = rt * 32 + wave * 8;
    if (base >= RN) return;

    const int k0 = (RN * ks) / KSPLIT;
    const int k1 = (RN * (ks + 1)) / KSPLIT;

    const float* wp[8];
#pragma unroll
    for (int r = 0; r < 8; ++r) {
        int row = base + r;
        if (row >= RN) row = RN - 1;
        row = __builtin_amdgcn_readfirstlane(row);
        wp[r] = W + (size_t)row * RN;
    }
    const float* ep = emb + (size_t)REGION_R0 * CH + c;

    float acc[8];
#pragma unroll
    for (int r = 0; r < 8; ++r) acc[r] = 0.0f;

    int k = k0;
    for (; k + 4 <= k1; k += 4) {
        const float e0 = ep[(size_t)(k + 0) * CH];
        const float e1 = ep[(size_t)(k + 1) * CH];
        const float e2 = ep[(size_t)(k + 2) * CH];
        const float e3 = ep[(size_t)(k + 3) * CH];
#pragma unroll
        for (int r = 0; r < 8; ++r) {
            const float* wr = wp[r];
            float a = acc[r];
            a = fmaf(wr[k + 0], e0, a);
            a = fmaf(wr[k + 1], e1, a);
            a = fmaf(wr[k + 2], e2, a);
            a = fmaf(wr[k + 3], e3, a);
            acc[r] = a;
        }
    }
    for (; k < k1; ++k) {
        const float e = ep[(size_t)k * CH];
#pragma unroll
        for (int r = 0; r < 8; ++r) acc[r] = fmaf(wp[r][k], e, acc[r]);
    }
#pragma unroll
    for (int r = 0; r < 8; ++r) {
        const int row = base + r;
        if (row < RN)
            unsafeAtomicAdd(region_ent + (size_t)row * CH + c, 0.2f * acc[r]);
    }
}

__device__ __forceinline__ float ent_val(const float* __restrict__ emb,
                                         const float* __restrict__ region_ent,
                                         int row, int c) {
    const float* p = (row >= REGION_R0 && row < REGION_R1)
                         ? (region_ent + (size_t)(row - REGION_R0) * CH + c)
                         : (emb + (size_t)row * CH + c);
    return *p;
}

__device__ __forceinline__ const float* ent_row(const float* __restrict__ emb,
                                                const float* __restrict__ region_ent,
                                                int row) {
    return (row >= REGION_R0 && row < REGION_R1)
               ? (region_ent + (size_t)(row - REGION_R0) * CH)
               : (emb + (size_t)row * CH);
}

// =========================================================================
// bf16 entity table (region rows baked in)
// =========================================================================
__global__ void build_ebf_kernel(const float* __restrict__ emb,
                                 const float* __restrict__ region_ent,
                                 ushort_t* __restrict__ ebf,
                                 int n_entities) {
    const int gid = blockIdx.x * blockDim.x + threadIdx.x;
    if (gid >= n_entities * (CH / 8)) return;
    const int row = gid >> 3;
    const int co  = (gid & 7) * 8;
    const float* rp = ent_row(emb, region_ent, row) + co;
    const float4 a = *reinterpret_cast<const float4*>(rp);
    const float4 b = *reinterpret_cast<const float4*>(rp + 4);
    uint4 o;
    o.x = pack2bf(a.x, a.y);
    o.y = pack2bf(a.z, a.w);
    o.z = pack2bf(b.x, b.y);
    o.w = pack2bf(b.z, b.w);
    *reinterpret_cast<uint4*>(ebf + (size_t)row * CH + co) = o;
}

__device__ __forceinline__ float bf_lo(unsigned u) { return __uint_as_float(u << 16); }
__device__ __forceinline__ float bf_hi(unsigned u) { return __uint_as_float(u & 0xffff0000u); }

// =========================================================================
// CSR build, XCD-sliced. R15: grid = NSLICE*SLICE_RB = 1024 blocks so the
// whole grid is co-resident at launch -> blockIdx%8 -> XCD binding stable.
// =========================================================================
__global__ void hist_sliced_kernel(const int* __restrict__ keys,
                                   int* __restrict__ counts, int n, unsigned smul) {
    const int slice = blockIdx.x & (NSLICE - 1);
    const int rb    = blockIdx.x >> 3;
    const int nrb   = gridDim.x >> 3;
    const int per   = (n + nrb - 1) / nrb;
    const int i0    = rb * per;
    const int i1    = min(i0 + per, n);
    for (int i = i0 + (int)threadIdx.x; i < i1; i += blockDim.x) {
        const int k = keys[i];
        if ((int)__umulhi((unsigned)k, smul) == slice)
            atomicAdd(&counts[k], 1);
    }
}

__global__ void scan_block_kernel(const int* __restrict__ counts, int* __restrict__ offs,
                                  int* __restrict__ bsums, int n) {
    __shared__ int s[SCAN_B];
    const int i = blockIdx.x * SCAN_B + threadIdx.x;
    s[threadIdx.x] = (i < n) ? counts[i] : 0;
    __syncthreads();
    for (int d = 1; d < SCAN_B; d <<= 1) {
        const int t = (threadIdx.x >= d) ? s[threadIdx.x - d] : 0;
        __syncthreads();
        s[threadIdx.x] += t;
        __syncthreads();
    }
    if (i < n) offs[i + 1] = s[threadIdx.x];
    if (threadIdx.x == SCAN_B - 1) bsums[blockIdx.x] = s[threadIdx.x];
    if (blockIdx.x == 0 && threadIdx.x == 0) offs[0] = 0;
}

__global__ void scan_top_kernel(int* __restrict__ bsums, int nb) {
    __shared__ int s[512];
    s[threadIdx.x] = (threadIdx.x < (unsigned)nb) ? bsums[threadIdx.x] : 0;
    __syncthreads();
    for (int d = 1; d < 512; d <<= 1) {
        const int t = (threadIdx.x >= d) ? s[threadIdx.x - d] : 0;
        __syncthreads();
        s[threadIdx.x] += t;
        __syncthreads();
    }
    if (threadIdx.x < (unsigned)nb) bsums[threadIdx.x] = s[threadIdx.x];
}

__global__ void scan_add_kernel(int* __restrict__ offs, const int* __restrict__ bsums, int n) {
    if (blockIdx.x == 0) return;
    const int i = blockIdx.x * SCAN_B + threadIdx.x;
    if (i < n) offs[i + 1] += bsums[blockIdx.x - 1];
}

// sorted_tr[pos] = tail | (rel<<17)  (tail<2^17, rel<2^5)
__global__ void scatter_e_sliced_kernel(const int* __restrict__ edge_index,
                                        const int* __restrict__ edge_type,
                                        const int* __restrict__ offs,
                                        int* __restrict__ cursor,
                                        int* __restrict__ sorted_tr,
                                        int E, int n_rel, unsigned smul) {
    const int slice = blockIdx.x & (NSLICE - 1);
    const int rb    = blockIdx.x >> 3;
    const int nrb   = gridDim.x >> 3;
    const int per   = (E + nrb - 1) / nrb;
    const int e0    = rb * per;
    const int e1    = min(e0 + per, E);
    for (int e = e0 + (int)threadIdx.x; e < e1; e += blockDim.x) {
        const int h = edge_index[e];
        if ((int)__umulhi((unsigned)h, smul) != slice) continue;
        const int t = edge_index[(size_t)E + e];
        int r = edge_type[e] - 1;
        if (r < 0) r += n_rel;
        const int pos = offs[h] + atomicAdd(&cursor[h], 1);
        sorted_tr[pos] = t | (r << 17);
    }
}

__global__ void scatter_u_sliced_kernel(const int* __restrict__ irows,
                                        const int* __restrict__ icols,
                                        const float* __restrict__ ivals,
                                        const int* __restrict__ offs,
                                        int* __restrict__ cursor,
                                        uint2* __restrict__ upack,
                                        int NNZ, unsigned smul) {
    const int slice = blockIdx.x & (NSLICE - 1);
    const int rb    = blockIdx.x >> 3;
    const int nrb   = gridDim.x >> 3;
    const int per   = (NNZ + nrb - 1) / nrb;
    const int i0    = rb * per;
    const int i1    = min(i0 + per, NNZ);
    for (int i = i0 + (int)threadIdx.x; i < i1; i += blockDim.x) {
        const int u = irows[i];
        if ((int)__umulhi((unsigned)u, smul) != slice) continue;
        const int pos = offs[u] + atomicAdd(&cursor[u], 1);
        uint2 cv;
        cv.x = (unsigned)icols[i];
        cv.y = __float_as_uint(ivals[i]);
        upack[pos] = cv;
    }
}

// =========================================================================
// bf16 gather kernels. R15: unroll x4 fully predicated (16 rows in flight
// per wave, 4 independent loads per lane) for latency cover.
// lane = (g = lane>>4 edge slot, q = lane&15 channel quad)
// =========================================================================
__global__ void kg_gather_bf_kernel(const ushort_t* __restrict__ ebf,
                                    const int* __restrict__ sorted_tr,
                                    const int* __restrict__ offs,
                                    const float* __restrict__ weight,
                                    float* __restrict__ out_ent,
                                    int n_entities, int n_rel) {
    extern __shared__ float wl[];   // n_rel * CH
    for (int i = threadIdx.x; i < n_rel * CH; i += blockDim.x) wl[i] = weight[i];
    __syncthreads();
    const float4* wl4 = reinterpret_cast<const float4*>(wl);

    const int wid  = (blockIdx.x * blockDim.x + threadIdx.x) >> 6;
    const int lane = threadIdx.x & 63;
    const int g    = lane >> 4;
    const int q    = lane & 15;
    if (wid >= n_entities) return;

    const int s0 = offs[wid], s1 = offs[wid + 1];
    float ax[4], ay[4], az[4], aw[4];
#pragma unroll
    for (int u = 0; u < 4; ++u) { ax[u] = 0.f; ay[u] = 0.f; az[u] = 0.f; aw[u] = 0.f; }

    for (int base = s0; base < s1; base += 16) {
#pragma unroll
        for (int u = 0; u < 4; ++u) {
            const int e = base + u * 4 + g;
            const bool valid = (e < s1);
            const int tr = valid ? sorted_tr[e] : 0;
            uint2 p; p.x = 0u; p.y = 0u;
            if (valid)
                p = *reinterpret_cast<const uint2*>(
                    ebf + (size_t)(tr & 0x1FFFF) * CH + q * 4);
            const float4 wv = wl4[(tr >> 17) * 16 + q];
            ax[u] = fmaf(bf_lo(p.x), wv.x, ax[u]);
            ay[u] = fmaf(bf_hi(p.x), wv.y, ay[u]);
            az[u] = fmaf(bf_lo(p.y), wv.z, az[u]);
            aw[u] = fmaf(bf_hi(p.y), wv.w, aw[u]);
        }
    }
    float AX = (ax[0] + ax[1]) + (ax[2] + ax[3]);
    float AY = (ay[0] + ay[1]) + (ay[2] + ay[3]);
    float AZ = (az[0] + az[1]) + (az[2] + az[3]);
    float AW = (aw[0] + aw[1]) + (aw[2] + aw[3]);

    AX += __shfl_xor(AX, 16); AY += __shfl_xor(AY, 16);
    AZ += __shfl_xor(AZ, 16); AW += __shfl_xor(AW, 16);
    AX += __shfl_xor(AX, 32); AY += __shfl_xor(AY, 32);
    AZ += __shfl_xor(AZ, 32); AW += __shfl_xor(AW, 32);

    if (g == 0) {
        const int deg = s1 - s0;
        const float inv = 1.0f / (float)(deg > 0 ? deg : 1);
        float4 o;
        o.x = AX * inv; o.y = AY * inv; o.z = AZ * inv; o.w = AW * inv;
        reinterpret_cast<float4*>(out_ent + (size_t)wid * CH)[q] = o;
    }
}

__global__ void user_gather_bf_kernel(const ushort_t* __restrict__ ebf,
                                      const uint2* __restrict__ upack,
                                      const int* __restrict__ offs,
                                      float* __restrict__ out_user,
                                      int n_users) {
    const int wid  = (blockIdx.x * blockDim.x + threadIdx.x) >> 6;
    const int lane = threadIdx.x & 63;
    const int g    = lane >> 4;
    const int q    = lane & 15;
    if (wid >= n_users) return;

    const int s0 = offs[wid], s1 = offs[wid + 1];
    float ax[4], ay[4], az[4], aw[4];
#pragma unroll
    for (int u = 0; u < 4; ++u) { ax[u] = 0.f; ay[u] = 0.f; az[u] = 0.f; aw[u] = 0.f; }

    for (int base = s0; base < s1; base += 16) {
#pragma unroll
        for (int u = 0; u < 4; ++u) {
            const int e = base + u * 4 + g;
            const bool valid = (e < s1);
            uint2 cv; cv.x = 0u; cv.y = 0u;
            if (valid) cv = upack[e];
            const float v = __uint_as_float(cv.y);   // 0 when invalid
            const uint2 p = *reinterpret_cast<const uint2*>(
                ebf + (size_t)cv.x * CH + q * 4);    // row 0 is valid memory
            ax[u] = fmaf(v, bf_lo(p.x), ax[u]);
            ay[u] = fmaf(v, bf_hi(p.x), ay[u]);
            az[u] = fmaf(v, bf_lo(p.y), az[u]);
            aw[u] = fmaf(v, bf_hi(p.y), aw[u]);
        }
    }
    float AX = (ax[0] + ax[1]) + (ax[2] + ax[3]);
    float AY = (ay[0] + ay[1]) + (ay[2] + ay[3]);
    float AZ = (az[0] + az[1]) + (az[2] + az[3]);
    float AW = (aw[0] + aw[1]) + (aw[2] + aw[3]);

    AX += __shfl_xor(AX, 16); AY += __shfl_xor(AY, 16);
    AZ += __shfl_xor(AZ, 16); AW += __shfl_xor(AW, 16);
    AX += __shfl_xor(AX, 32); AY += __shfl_xor(AY, 32);
    AZ += __shfl_xor(AZ, 32); AW += __shfl_xor(AW, 32);

    if (g == 0) {
        float4 o; o.x = AX; o.y = AY; o.z = AZ; o.w = AW;
        reinterpret_cast<float4*>(out_user + (size_t)wid * CH)[q] = o;
    }
}

// =========================================================================
// fp32 gather kernels (fallback when ws can't fit ebf)
// =========================================================================
__global__ void kg_gather_kernel(const float* __restrict__ emb,
                                 const float* __restrict__ region_ent,
                                 const int* __restrict__ sorted_tr,
                                 const int* __restrict__ offs,
                                 const float* __restrict__ weight,
                                 float* __restrict__ out_ent,
                                 int n_entities, int n_rel) {
    extern __shared__ float wl[];
    for (int i = threadIdx.x; i < n_rel * CH; i += blockDim.x) wl[i] = weight[i];
    __syncthreads();
    const float4* wl4 = reinterpret_cast<const float4*>(wl);

    const int wid  = (blockIdx.x * blockDim.x + threadIdx.x) >> 6;
    const int lane = threadIdx.x & 63;
    const int g    = lane >> 4;
    const int q    = lane & 15;
    if (wid >= n_entities) return;

    const int s0 = offs[wid], s1 = offs[wid + 1];
    float ax = 0.0f, ay = 0.0f, az = 0.0f, aw = 0.0f;

    for (int base = s0; base < s1; base += 4) {
        const int e = base + g;
        const bool valid = (e < s1);
        const int tr   = valid ? sorted_tr[e] : 0;
        const int tail = tr & 0x1FFFF;
        const int rel  = tr >> 17;
        const float4* rp = reinterpret_cast<const float4*>(ent_row(emb, region_ent, tail));
        float4 ev;
        if (valid) ev = rp[q];
        else       { ev.x = 0.0f; ev.y = 0.0f; ev.z = 0.0f; ev.w = 0.0f; }
        const float4 wv = wl4[rel * 16 + q];
        ax = fmaf(ev.x, wv.x, ax);
        ay = fmaf(ev.y, wv.y, ay);
        az = fmaf(ev.z, wv.z, az);
        aw = fmaf(ev.w, wv.w, aw);
    }

    ax += __shfl_xor(ax, 16); ay += __shfl_xor(ay, 16);
    az += __shfl_xor(az, 16); aw += __shfl_xor(aw, 16);
    ax += __shfl_xor(ax, 32); ay += __shfl_xor(ay, 32);
    az += __shfl_xor(az, 32); aw += __shfl_xor(aw, 32);

    if (g == 0) {
        const int deg = s1 - s0;
        const float inv = 1.0f / (float)(deg > 0 ? deg : 1);
        float4 o;
        o.x = ax * inv; o.y = ay * inv; o.z = az * inv; o.w = aw * inv;
        reinterpret_cast<float4*>(out_ent + (size_t)wid * CH)[q] = o;
    }
}

__global__ void user_gather_kernel(const float* __restrict__ emb,
                                   const float* __restrict__ region_ent,
                                   const uint2* __restrict__ upack,
                                   const int* __restrict__ offs,
                                   float* __restrict__ out_user,
                                   int n_users) {
    const int wid  = (blockIdx.x * blockDim.x + threadIdx.x) >> 6;
    const int lane = threadIdx.x & 63;
    const int g    = lane >> 4;
    const int q    = lane & 15;
    if (wid >= n_users) return;

    const int s0 = offs[wid], s1 = offs[wid + 1];
    float ax = 0.0f, ay = 0.0f, az = 0.0f, aw = 0.0f;

    for (int base = s0; base < s1; base += 4) {
        const int e = base + g;
        const bool valid = (e < s1);
        uint2 cv;
        if (valid) cv = upack[e];
        else       { cv.x = 0u; cv.y = 0u; }
        const int   col = (int)cv.x;
        const float v   = __uint_as_float(cv.y);
        const float4* rp = reinterpret_cast<const float4*>(ent_row(emb, region_ent, col));
        const float4 ev = rp[q];
        ax = fmaf(v, ev.x, ax);
        ay = fmaf(v, ev.y, ay);
        az = fmaf(v, ev.z, az);
        aw = fmaf(v, ev.w, aw);
    }

    ax += __shfl_xor(ax, 16); ay += __shfl_xor(ay, 16);
    az += __shfl_xor(az, 16); aw += __shfl_xor(aw, 16);
    ax += __shfl_xor(ax, 32); ay += __shfl_xor(ay, 32);
    az += __shfl_xor(az, 32); aw += __shfl_xor(aw, 32);

    if (g == 0) {
        float4 o; o.x = ax; o.y = ay; o.z = az; o.w = aw;
        reinterpret_cast<float4*>(out_user + (size_t)wid * CH)[q] = o;
    }
}

// =========================================================================
// Fallback (small ws): packed-row atomic scatter
// =========================================================================
__global__ void kg_agg_atomic_kernel(const float* __restrict__ emb,
                                     const float* __restrict__ region_ent,
                                     const int* __restrict__ edge_index,
                                     const int* __restrict__ edge_type,
                                     const float* __restrict__ weight,
                                     float* __restrict__ out_ent,
                                     float* __restrict__ counts,
                                     int E, int n_rel) {
    const long long gid = (long long)blockIdx.x * blockDim.x + threadIdx.x;
    const long long e = gid >> 6;
    if (e >= E) return;
    const int c = (int)gid & 63;
    const int h = edge_index[e];
    const int t = edge_index[(size_t)E + e];
    int r = edge_type[e] - 1;
    if (r < 0) r += n_rel;
    const float v = ent_val(emb, region_ent, t, c) * weight[(size_t)r * CH + c];
    unsafeAtomicAdd(out_ent + (size_t)h * CH + c, v);
    if (c == 0) unsafeAtomicAdd(counts + h, 1.0f);
}

__global__ void user_agg_atomic_kernel(const float* __restrict__ emb,
                                       const float* __restrict__ region_ent,
                                       const int* __restrict__ irows,
                                       const int* __restrict__ icols,
                                       const float* __restrict__ ivals,
                                       float* __restrict__ out_user, int NNZ) {
    const long long gid = (long long)blockIdx.x * blockDim.x + threadIdx.x;
    const long long i = gid >> 6;
    if (i >= NNZ) return;
    const int c = (int)gid & 63;
    const float v = ivals[i] * ent_val(emb, region_ent, icols[i], c);
    unsafeAtomicAdd(out_user + (size_t)irows[i] * CH + c, v);
}

__global__ void finalize_kernel(float* __restrict__ out_ent,
                                const float* __restrict__ counts, int n_entities) {
    const int gid = blockIdx.x * blockDim.x + threadIdx.x;
    if (gid >= n_entities * CH) return;
    out_ent[gid] /= fmaxf(counts[gid >> 6], 1.0f);
}

// =========================================================================
extern "C" void kernel_launch(void* const* d_in, const int* in_sizes, int n_in,
                              void* d_out, int out_size, void* d_ws, size_t ws_size,
                              hipStream_t stream) {
    const float* entity_emb = (const float*)d_in[0];
    const int*   edge_index = (const int*)d_in[2];
    const int*   edge_type  = (const int*)d_in[3];
    const int*   irows      = (const int*)d_in[4];
    const int*   icols      = (const int*)d_in[5];
    const float* ivals      = (const float*)d_in[6];
    const float* Wreg       = (const float*)d_in[7];
    const float* weight     = (const float*)d_in[8];

    const int n_entities = in_sizes[0] / CH;
    const int n_users    = in_sizes[1] / CH;
    const int E          = in_sizes[3];
    const int NNZ        = in_sizes[4];
    const int n_rel      = in_sizes[8] / CH;

    float* out_ent  = (float*)d_out;
    float* out_user = out_ent + (size_t)n_entities * CH;

    // slice magics: slice(k) = umulhi(k, smul) in [0, 8)
    const unsigned smul_e = (unsigned)((8ULL << 32) / (unsigned long long)n_entities);
    const unsigned smul_u = (unsigned)((8ULL << 32) / (unsigned long long)n_users);

    // ---- workspace layout (8B-aligned) ----
    char* w = (char*)d_ws;
    auto take = [&](size_t bytes) {
        char* p = w;
        w += (bytes + 7) & ~(size_t)7;
        return p;
    };
    float*    region_ent = (float*)take((size_t)RN * CH * 4);
    int*      offs_e     = (int*)take((size_t)(n_entities + 1) * 4);
    int*      cursor_e   = (int*)take((size_t)n_entities * 4);
    int*      offs_u     = (int*)take((size_t)(n_users + 1) * 4);
    int*      cursor_u   = (int*)take((size_t)n_users * 4);
    int*      bsums      = (int*)take(512 * 4);
    int*      sorted_tr  = (int*)take((size_t)E * 4);
    uint2*    upack      = (uint2*)take((size_t)NNZ * 8);
    ushort_t* e_t        = (ushort_t*)take((size_t)CH * KP * 2);
    const size_t need_csr = (size_t)(w - (char*)d_ws);
    ushort_t* ebf        = (ushort_t*)take((size_t)n_entities * CH * 2);
    const size_t need_bf  = (size_t)(w - (char*)d_ws);

    const int nb_e = (n_entities + SCAN_B - 1) / SCAN_B;
    const int nb_u = (n_users + SCAN_B - 1) / SCAN_B;
    const bool use_csr = (ws_size >= need_csr) && (nb_e <= 512) && (nb_u <= 512) &&
                         (n_entities < (1 << 17)) && (n_rel <= 32);
    const bool use_bf  = use_csr && (ws_size >= need_bf);

    // ---- region blend ----
    region_init_kernel<<<(RN * CH / 4 + 255) / 256, 256, 0, stream>>>(entity_emb, region_ent);

    if (use_csr) {
        // MFMA region GEMM (bf16 inputs, fp32 accum)
        {
            const int tot = CH * (KP / 8);
            build_et_kernel<<<(tot + 255) / 256, 256, 0, stream>>>(entity_emb, e_t);
        }
        region_gemm_mfma_kernel<<<MT_BLKS * KCHUNKS, 256, 0, stream>>>(
            Wreg, e_t, region_ent);

        if (use_bf) {
            const int tot = n_entities * (CH / 8);
            build_ebf_kernel<<<(tot + 255) / 256, 256, 0, stream>>>(
                entity_emb, region_ent, ebf, n_entities);
        }

        hipMemsetAsync(cursor_e, 0, (size_t)n_entities * 4, stream);
        hipMemsetAsync(cursor_u, 0, (size_t)n_users * 4, stream);

        // sliced histograms (grid co-resident: 8 slices x 128 ranges)
        hist_sliced_kernel<<<NSLICE * SLICE_RB, 256, 0, stream>>>(
            edge_index, cursor_e, E, smul_e);
        hist_sliced_kernel<<<NSLICE * SLICE_RB, 256, 0, stream>>>(
            irows, cursor_u, NNZ, smul_u);

        scan_block_kernel<<<nb_e, SCAN_B, 0, stream>>>(cursor_e, offs_e, bsums, n_entities);
        scan_top_kernel<<<1, 512, 0, stream>>>(bsums, nb_e);
        scan_add_kernel<<<nb_e, SCAN_B, 0, stream>>>(offs_e, bsums, n_entities);

        scan_block_kernel<<<nb_u, SCAN_B, 0, stream>>>(cursor_u, offs_u, bsums, n_users);
        scan_top_kernel<<<1, 512, 0, stream>>>(bsums, nb_u);
        scan_add_kernel<<<nb_u, SCAN_B, 0, stream>>>(offs_u, bsums, n_users);

        hipMemsetAsync(cursor_e, 0, (size_t)n_entities * 4, stream);
        hipMemsetAsync(cursor_u, 0, (size_t)n_users * 4, stream);

        // sliced scatters (co-resident grids)
        scatter_e_sliced_kernel<<<NSLICE * SLICE_RB, 256, 0, stream>>>(
            edge_index, edge_type, offs_e, cursor_e, sorted_tr, E, n_rel, smul_e);
        scatter_u_sliced_kernel<<<NSLICE * SLICE_RB, 256, 0, stream>>>(
            irows, icols, ivals, offs_u, cursor_u, upack, NNZ, smul_u);

        if (use_bf) {
            kg_gather_bf_kernel<<<(n_entities + 3) / 4, 256, n_rel * CH * 4, stream>>>(
                ebf, sorted_tr, offs_e, weight, out_ent, n_entities, n_rel);
            user_gather_bf_kernel<<<(n_users + 3) / 4, 256, 0, stream>>>(
                ebf, upack, offs_u, out_user, n_users);
        } else {
            kg_gather_kernel<<<(n_entities + 3) / 4, 256, n_rel * CH * 4, stream>>>(
                entity_emb, region_ent, sorted_tr, offs_e, weight, out_ent, n_entities, n_rel);
            user_gather_kernel<<<(n_users + 3) / 4, 256, 0, stream>>>(
                entity_emb, region_ent, upack, offs_u, out_user, n_users);
        }
    } else {
        // fallback: old VALU region gemm + packed-row atomics
        region_gemm_kernel<<<ROW_TILES * KSPLIT, 256, 0, stream>>>(
            entity_emb, Wreg, region_ent);

        float* counts = (float*)((char*)d_ws + (((size_t)RN * CH * 4 + 7) & ~(size_t)7));
        hipMemsetAsync(d_out, 0, (size_t)out_size * sizeof(float), stream);
        hipMemsetAsync(counts, 0, (size_t)n_entities * sizeof(float), stream);

        {
            const long long tot = (long long)E * CH;
            kg_agg_atomic_kernel<<<(int)((tot + 255) / 256), 256, 0, stream>>>(
                entity_emb, region_ent, edge_index, edge_type, weight,
                out_ent, counts, E, n_rel);
        }
        {
            const long long tot = (long long)NNZ * CH;
            user_agg_atomic_kernel<<<(int)((tot + 255) / 256), 256, 0, stream>>>(
                entity_emb, region_ent, irows, icols, ivals, out_user, NNZ);
        }
        finalize_kernel<<<(n_entities * CH + 255) / 256, 256, 0, stream>>>(
            out_ent, counts, n_entities);
    }
}